// Round 3
// baseline (72.001 us; speedup 1.0000x reference)
//
#include <hip/hip_runtime.h>
#include <hip/hip_bf16.h>

// b=8, H=8, n=1024, d=32, fp32 in, scalar MSE loss out.
// Per (b,h) pair p: Qt[d][n] = f_s[p*32768 + d*1024 + n]. sim = QK^T (unscaled),
// softmax over j, out = PV, loss = mean((out - f_t)^2).
//
// Block = 512 thr (8 waves), 128 q-rows (16/wave). Grid = 512, XCD swizzle.
// K: LDS double-buffer (chunk layout), staged by all 8 waves, reg-prefetched.
// V: NO LDS -- B-fragments are j-contiguous in global, loaded direct + packed.
// P: per-wave LDS tile (XOR-swizzled). One barrier per KV tile (64 rows).

typedef __attribute__((ext_vector_type(4))) float f32x4;
typedef __attribute__((ext_vector_type(8))) short bf16x8;
typedef __attribute__((ext_vector_type(4))) unsigned u32x4;

#define QOFF 0         // 8 x 1KB Q subtiles (chunk layout, per-wave)
#define KOFF 8192      // 2 x 4KB K double buffer (chunk layout)
#define POFF 16384     // 8 waves x 2KB P tile [16 i][64 j] bf16, XOR-swizzled
#define ROFF 32768     // 8 floats block reduction

__device__ __forceinline__ unsigned bfpack2(float a, float b) {
    // RNE f32->bf16 pair pack (finite inputs)
    unsigned ua = __float_as_uint(a), ub = __float_as_uint(b);
    ua += 0x7fffu + ((ua >> 16) & 1u);
    ub += 0x7fffu + ((ub >> 16) & 1u);
    return (ua >> 16) | (ub & 0xffff0000u);
}

__global__ __launch_bounds__(512, 4)
void attn_mse_kernel(const float* __restrict__ fs, const float* __restrict__ ft,
                     float* __restrict__ out)
{
    __shared__ __align__(16) unsigned char smem[32800];

    const int tid  = threadIdx.x;
    const int lane = tid & 63;
    const int w    = tid >> 6;     // wave 0..7
    const int g    = lane >> 4;    // 0..3
    const int c    = lane & 15;

    // XCD swizzle: all 8 q-blocks of a pair share bid%8 -> 2MB/XCD L2 set.
    const int bid  = blockIdx.x;
    const int x    = bid & 7, y = bid >> 3;
    const int pair = x * 8 + (y & 7);
    const int q0   = (y >> 3) * 128;

    const float* qb = fs + (size_t)pair * 32768;  // Q and V source
    const float* kb = ft + (size_t)pair * 32768;  // K source + loss target

    // ---- stage Q rows q0 + w*16..+15 (wave-own region, no barrier needed)
    {
        unsigned* lq = (unsigned*)(smem + QOFF) + w * 256;
        const int row0 = q0 + w * 16;
        #pragma unroll
        for (int p = 0; p < 4; ++p) {
            const int dp = 4 * p + g;
            const float* src = qb + (size_t)(2 * dp) * 1024 + row0 + c;
            lq[p * 64 + c * 4 + g] = bfpack2(src[0], src[1024]);
        }
    }
    const bf16x8 qf = *(const bf16x8*)(smem + QOFF + w * 1024 + lane * 16);

    // ---- K staging split over 8 waves: wave w -> subtile s=w>>1, chunk-pair h=w&1
    const int s_k = w >> 1, h_k = w & 1;
    float kr[4];
    auto LOADK = [&](int t) {
        const int row0 = t * 64 + s_k * 16;
        #pragma unroll
        for (int pp = 0; pp < 2; ++pp) {
            const int dp = 4 * (2 * h_k + pp) + g;
            const float* src = kb + (size_t)(2 * dp) * 1024 + row0 + c;
            kr[2 * pp] = src[0]; kr[2 * pp + 1] = src[1024];
        }
    };
    auto STOREK = [&](int buf) {
        unsigned* lk = (unsigned*)(smem + KOFF + buf * 4096) + s_k * 256;
        #pragma unroll
        for (int pp = 0; pp < 2; ++pp) {
            const int p = 2 * h_k + pp;
            lk[p * 64 + c * 4 + g] = bfpack2(kr[2 * pp], kr[2 * pp + 1]);
        }
    };

    LOADK(0);
    STOREK(0);

    f32x4 O0 = {0.f, 0.f, 0.f, 0.f}, O1 = {0.f, 0.f, 0.f, 0.f};
    float l_run = 0.f;                       // softmax denom partial for q-row i=c
    unsigned char* lp = smem + POFF + w * 2048;
    const float* vbase = qb + (size_t)c * 1024 + 8 * g;  // V fragment base (d=c row)

    int cur = 0;
    for (int t = 0; t < 16; ++t) {
        if (t < 15) LOADK(t + 1);            // reg prefetch, in flight across barrier

        // V fragments for THIS tile: d = c (hf=0) / c+16 (hf=1), j = t*64+ks*32+8g..+7
        float4 vr[8];
        {
            const float* vb0 = vbase + t * 64;
            #pragma unroll
            for (int ks = 0; ks < 2; ++ks)
                #pragma unroll
                for (int hf = 0; hf < 2; ++hf) {
                    const float* p = vb0 + (size_t)hf * 16384 + ks * 32;
                    vr[(ks * 2 + hf) * 2 + 0] = *(const float4*)(p);
                    vr[(ks * 2 + hf) * 2 + 1] = *(const float4*)(p + 4);
                }
        }

        __syncthreads();                     // K buf[cur] ready
        const unsigned char* bK = smem + KOFF + cur * 4096;

        // ST = K * Q^T : lane holds j = Mt*16 + 4g + r, i = c
        f32x4 S[4];
        #pragma unroll
        for (int Mt = 0; Mt < 4; ++Mt) {
            const bf16x8 kf = *(const bf16x8*)(bK + Mt * 1024 + lane * 16);
            const f32x4 z = {0.f, 0.f, 0.f, 0.f};
            S[Mt] = __builtin_amdgcn_mfma_f32_16x16x32_bf16(kf, qf, z, 0, 0, 0);
        }

        // P = exp(S) (no max subtraction: |S| <= ~34, fp32-safe)
        float ps = 0.f;
        #pragma unroll
        for (int Mt = 0; Mt < 4; ++Mt)
            #pragma unroll
            for (int rI = 0; rI < 4; ++rI) {
                const float p = __expf(S[Mt][rI]);
                S[Mt][rI] = p; ps += p;
            }
        l_run += ps;

        // P^T into per-wave tile [i=c][j] (wave-local, no barrier)
        #pragma unroll
        for (int Mt = 0; Mt < 4; ++Mt) {
            const unsigned lo = bfpack2(S[Mt][0], S[Mt][1]);
            const unsigned hi = bfpack2(S[Mt][2], S[Mt][3]);
            *(unsigned long long*)(lp + c * 128 +
                (((unsigned)(Mt * 32 + g * 8)) ^ ((c & 7) << 4))) =
                (unsigned long long)lo | ((unsigned long long)hi << 32);
        }

        // pack V fragments (f32 regs -> bf16x8), then O += P * V
        bf16x8 vf[4];
        #pragma unroll
        for (int f = 0; f < 4; ++f) {
            const float4 a = vr[2 * f], b = vr[2 * f + 1];
            const u32x4 u = {bfpack2(a.x, a.y), bfpack2(a.z, a.w),
                             bfpack2(b.x, b.y), bfpack2(b.z, b.w)};
            vf[f] = __builtin_bit_cast(bf16x8, u);
        }
        #pragma unroll
        for (int ks = 0; ks < 2; ++ks) {
            const unsigned cb = ((unsigned)(ks * 64 + g * 16)) ^ ((c & 7) << 4);
            const bf16x8 pa = *(const bf16x8*)(lp + c * 128 + cb);
            O0 = __builtin_amdgcn_mfma_f32_16x16x32_bf16(pa, vf[2 * ks + 0], O0, 0, 0, 0);
            O1 = __builtin_amdgcn_mfma_f32_16x16x32_bf16(pa, vf[2 * ks + 1], O1, 0, 0, 0);
        }

        if (t < 15) STOREK(cur ^ 1);         // fill next K buffer (read next iter)
        cur ^= 1;
    }

    // ---- softmax denominators (reduce over g groups)
    l_run += __shfl_xor(l_run, 16);
    l_run += __shfl_xor(l_run, 32);
    const float li = 1.0f / l_run;

    // ---- loss: lane holds O rows i = 4g+r, cols d = c / c+16
    float acc = 0.f;
    const int n0 = q0 + w * 16;
    #pragma unroll
    for (int rI = 0; rI < 4; ++rI) {
        const float lr = __shfl(li, g * 4 + rI);
        const int n = n0 + g * 4 + rI;
        #pragma unroll
        for (int Nd = 0; Nd < 2; ++Nd) {
            const int d = Nd * 16 + c;
            const float oo = (Nd ? O1[rI] : O0[rI]) * lr;
            const float tv = kb[(size_t)d * 1024 + n];
            const float e = oo - tv;
            acc += e * e;
        }
    }
    #pragma unroll
    for (int off = 1; off < 64; off <<= 1) acc += __shfl_xor(acc, off);
    float* lred = (float*)(smem + ROFF);
    if (lane == 0) lred[w] = acc;
    __syncthreads();
    if (tid == 0) {
        float s = 0.f;
        #pragma unroll
        for (int i = 0; i < 8; ++i) s += lred[i];
        atomicAdd(out, s * (1.0f / 2097152.0f));
    }
}

extern "C" void kernel_launch(void* const* d_in, const int* in_sizes, int n_in,
                              void* d_out, int out_size, void* d_ws, size_t ws_size,
                              hipStream_t stream) {
    const float* fs = (const float*)d_in[0];
    const float* ft = (const float*)d_in[1];
    float* out = (float*)d_out;
    hipMemsetAsync(out, 0, sizeof(float), stream);
    attn_mse_kernel<<<dim3(512), dim3(512), 0, stream>>>(fs, ft, out);
}

// Round 4
// 28.456 us; speedup vs baseline: 2.5303x; 2.5303x over previous
//
#include <hip/hip_runtime.h>
#include <hip/hip_bf16.h>

// b=8, H=8, n=1024, d=32, fp32 in, scalar MSE loss out.
// Per (b,h) pair p: Qt[d][n] = f_s[p*32768 + d*1024 + n]. sim = QK^T (unscaled),
// softmax over j, out = PV, loss = mean((out - f_t)^2).
//
// Block = 512 thr (8 waves), 32 q-rows/wave = 256 rows/block. Grid = 256 (1/CU),
// XCD swizzle (8 pairs per XCD -> 2MB L2 set). K,V: LDS double-buffered, staged
// by all 8 waves with register prefetch. P: NO LDS -- redistributed in-register
// via v_cvt_pk_bf16_f32 + v_permlane32/16_swap. Softmax as exp2 (Q pre-scaled
// by log2 e). One barrier per 64-row KV tile.

typedef __attribute__((ext_vector_type(4))) float f32x4;
typedef __attribute__((ext_vector_type(8))) short bf16x8;
typedef __attribute__((ext_vector_type(4))) unsigned u32x4;

#define QOFF 0         // 8 waves x 2KB (two 16-row chunk-layout subtiles each)
#define KOFF 16384     // 2 x 4KB K double buffer (chunk layout)
#define VOFF 24576     // 2 x 4KB V double buffer ([d][j] bf16, XOR-swizzled)
#define ROFF 32768     // 8 floats block reduction

__device__ __forceinline__ unsigned cvtpk(float a, float b) {
    unsigned r;  // r.lo = bf16(a), r.hi = bf16(b), RNE
    asm("v_cvt_pk_bf16_f32 %0, %1, %2" : "=v"(r) : "v"(a), "v"(b));
    return r;
}
#define SWAP32(a, b) asm("v_permlane32_swap_b32 %0, %1" : "+v"(a), "+v"(b))
#define SWAP16(a, b) asm("v_permlane16_swap_b32 %0, %1" : "+v"(a), "+v"(b))

__device__ __forceinline__ float exp2fast(float x) {
#if __has_builtin(__builtin_amdgcn_exp2f)
    return __builtin_amdgcn_exp2f(x);
#else
    return exp2f(x);
#endif
}

__global__ __launch_bounds__(512, 2)
void attn_mse_kernel(const float* __restrict__ fs, const float* __restrict__ ft,
                     float* __restrict__ out)
{
    __shared__ __align__(16) unsigned char smem[32832];

    const int tid  = threadIdx.x;
    const int lane = tid & 63;
    const int w    = tid >> 6;     // wave 0..7
    const int g    = lane >> 4;    // 0..3
    const int c    = lane & 15;

    // XCD swizzle: 8 pairs x 4 q-blocks per XCD (bid%8).
    const int bid  = blockIdx.x;
    const int x    = bid & 7, y = bid >> 3;
    const int pair = x * 8 + (y & 7);
    const int q0   = (y >> 3) * 256;

    const float* qb = fs + (size_t)pair * 32768;  // Q and V source
    const float* kb = ft + (size_t)pair * 32768;  // K source + loss target

    // ---- stage Q (2 subtiles x 16 rows per wave), pre-scaled by log2(e)
    {
        unsigned* lq = (unsigned*)(smem + QOFF) + w * 512;
        #pragma unroll
        for (int is = 0; is < 2; ++is) {
            const int row0 = q0 + w * 32 + is * 16;
            #pragma unroll
            for (int p = 0; p < 4; ++p) {
                const int dp = 4 * p + g;
                const float* src = qb + (size_t)(2 * dp) * 1024 + row0 + c;
                lq[is * 256 + p * 64 + c * 4 + g] =
                    cvtpk(src[0] * 1.44269504f, src[1024] * 1.44269504f);
            }
        }
    }
    const bf16x8 qf0 = *(const bf16x8*)(smem + QOFF + w * 2048 + lane * 16);
    const bf16x8 qf1 = *(const bf16x8*)(smem + QOFF + w * 2048 + 1024 + lane * 16);

    // ---- K staging: wave w -> subtile s_k = w>>1, chunk-quad h_k = w&1
    const int s_k = w >> 1, h_k = w & 1;
    float  kr[4];
    float4 vr;                      // V prefetch: row d_v = w*4+g, 4 j-values
    const int d_v = w * 4 + g;

    auto LOADK = [&](int t) {
        const int row0 = t * 64 + s_k * 16;
        #pragma unroll
        for (int pp = 0; pp < 2; ++pp) {
            const int dp = 4 * (2 * h_k + pp) + g;
            const float* src = kb + (size_t)(2 * dp) * 1024 + row0 + c;
            kr[2 * pp] = src[0]; kr[2 * pp + 1] = src[1024];
        }
    };
    auto LOADV = [&](int t) {
        vr = *(const float4*)(qb + (size_t)d_v * 1024 + t * 64 + 4 * c);
    };
    auto STORE = [&](int buf) {
        unsigned* lk = (unsigned*)(smem + KOFF + buf * 4096) + s_k * 256;
        #pragma unroll
        for (int pp = 0; pp < 2; ++pp) {
            const int p = 2 * h_k + pp;
            lk[p * 64 + c * 4 + g] = cvtpk(kr[2 * pp], kr[2 * pp + 1]);
        }
        unsigned char* lv = smem + VOFF + buf * 4096;
        const unsigned lo = cvtpk(vr.x, vr.y), hi = cvtpk(vr.z, vr.w);
        *(unsigned long long*)(lv + d_v * 128 + ((8 * c) ^ ((d_v & 7) << 4))) =
            (unsigned long long)lo | ((unsigned long long)hi << 32);
    };

    LOADK(0); LOADV(0);
    STORE(0);

    f32x4 O[2][2];  // [i-subtile][d-half]
    #pragma unroll
    for (int a = 0; a < 2; ++a)
        #pragma unroll
        for (int b = 0; b < 2; ++b)
            O[a][b] = f32x4{0.f, 0.f, 0.f, 0.f};
    float l0 = 0.f, l1 = 0.f;  // softmax denom partials (q-row i = c, per subtile)

    int cur = 0;
    for (int t = 0; t < 16; ++t) {
        if (t < 15) { LOADK(t + 1); LOADV(t + 1); }   // reg prefetch across barrier
        __syncthreads();                              // buf[cur] ready
        const unsigned char* bK = smem + KOFF + cur * 4096;
        const unsigned char* bV = smem + VOFF + cur * 4096;

        // operand reads up front (8 x ds_read_b128, conflict-minimal)
        bf16x8 kf[4], vb[2][2];
        #pragma unroll
        for (int Mt = 0; Mt < 4; ++Mt)
            kf[Mt] = *(const bf16x8*)(bK + Mt * 1024 + lane * 16);
        #pragma unroll
        for (int ks = 0; ks < 2; ++ks)
            #pragma unroll
            for (int df = 0; df < 2; ++df)
                vb[ks][df] = *(const bf16x8*)(bV + (c + 16 * df) * 128 +
                               (((unsigned)(ks * 64 + g * 16)) ^ ((c & 7) << 4)));

        // ST = K * Q^T : lane holds j = 16Mt + 4g + r, i = c (per subtile)
        f32x4 S[4][2];
        #pragma unroll
        for (int Mt = 0; Mt < 4; ++Mt) {
            const f32x4 z = {0.f, 0.f, 0.f, 0.f};
            S[Mt][0] = __builtin_amdgcn_mfma_f32_16x16x32_bf16(kf[Mt], qf0, z, 0, 0, 0);
            S[Mt][1] = __builtin_amdgcn_mfma_f32_16x16x32_bf16(kf[Mt], qf1, z, 0, 0, 0);
        }

        // P = exp2(S') = exp(sim); no max subtraction (|S'| <= ~50, fp32-safe)
        float ps0 = 0.f, ps1 = 0.f;
        #pragma unroll
        for (int Mt = 0; Mt < 4; ++Mt)
            #pragma unroll
            for (int r = 0; r < 4; ++r) {
                const float p0 = exp2fast(S[Mt][0][r]);
                const float p1 = exp2fast(S[Mt][1][r]);
                S[Mt][0][r] = p0; ps0 += p0;
                S[Mt][1][r] = p1; ps1 += p1;
            }
        l0 += ps0; l1 += ps1;

        // P fragments in-register: cvt_pk pairs then permlane 32/16 swaps.
        // After swaps, lane (g,c) element e holds P[i=c][j = 32ks + 8g + e].
        #pragma unroll
        for (int is = 0; is < 2; ++is) {
            #pragma unroll
            for (int ks = 0; ks < 2; ++ks) {
                unsigned u0 = cvtpk(S[2 * ks][is][0],     S[2 * ks][is][1]);
                unsigned u1 = cvtpk(S[2 * ks][is][2],     S[2 * ks][is][3]);
                unsigned u2 = cvtpk(S[2 * ks + 1][is][0], S[2 * ks + 1][is][1]);
                unsigned u3 = cvtpk(S[2 * ks + 1][is][2], S[2 * ks + 1][is][3]);
                SWAP32(u0, u2); SWAP32(u1, u3);
                SWAP16(u0, u2); SWAP16(u1, u3);
                const u32x4 pw = {u0, u1, u2, u3};
                const bf16x8 pa = __builtin_bit_cast(bf16x8, pw);
                O[is][0] = __builtin_amdgcn_mfma_f32_16x16x32_bf16(pa, vb[ks][0], O[is][0], 0, 0, 0);
                O[is][1] = __builtin_amdgcn_mfma_f32_16x16x32_bf16(pa, vb[ks][1], O[is][1], 0, 0, 0);
            }
        }

        if (t < 15) STORE(cur ^ 1);   // fill next buffer (read next iter, post-barrier)
        cur ^= 1;
    }

    // ---- softmax denominators (reduce over g groups; lane gets row c's sum)
    l0 += __shfl_xor(l0, 16); l0 += __shfl_xor(l0, 32);
    l1 += __shfl_xor(l1, 16); l1 += __shfl_xor(l1, 32);
    const float li0 = 1.0f / l0;
    const float li1 = 1.0f / l1;

    // ---- loss: lane holds O rows i = 4g+r, cols d = c / c+16
    float acc = 0.f;
    const int n0 = q0 + w * 32;
    #pragma unroll
    for (int is = 0; is < 2; ++is) {
        const float liv = is ? li1 : li0;
        #pragma unroll
        for (int r = 0; r < 4; ++r) {
            const float lr = __shfl(liv, g * 4 + r);  // denom of local row 4g+r
            const int n = n0 + is * 16 + g * 4 + r;
            #pragma unroll
            for (int Nd = 0; Nd < 2; ++Nd) {
                const int d = Nd * 16 + c;
                const float oo = O[is][Nd][r] * lr;
                const float tv = kb[(size_t)d * 1024 + n];
                const float e = oo - tv;
                acc += e * e;
            }
        }
    }
    #pragma unroll
    for (int off = 1; off < 64; off <<= 1) acc += __shfl_xor(acc, off);
    float* lred = (float*)(smem + ROFF);
    if (lane == 0) lred[w] = acc;
    __syncthreads();
    if (tid == 0) {
        float s = 0.f;
        #pragma unroll
        for (int i = 0; i < 8; ++i) s += lred[i];
        atomicAdd(out, s * (1.0f / 2097152.0f));
    }
}

extern "C" void kernel_launch(void* const* d_in, const int* in_sizes, int n_in,
                              void* d_out, int out_size, void* d_ws, size_t ws_size,
                              hipStream_t stream) {
    const float* fs = (const float*)d_in[0];
    const float* ft = (const float*)d_in[1];
    float* out = (float*)d_out;
    hipMemsetAsync(out, 0, sizeof(float), stream);
    attn_mse_kernel<<<dim3(256), dim3(512), 0, stream>>>(fs, ft, out);
}

// Round 5
// 28.024 us; speedup vs baseline: 2.5693x; 1.0154x over previous
//
#include <hip/hip_runtime.h>
#include <hip/hip_bf16.h>

// b=8, H=8, n=1024, d=32, fp32 in, scalar MSE loss out.
// Per pair p: Qt[d][n] = f_s[p*32768 + d*1024 + n]. sim = QK^T (unscaled),
// softmax over j, out = PV, loss = mean((out - f_t)^2).
//
// Block = 512 thr (8 waves), 32 q-rows/wave = 256 rows. Grid = 256 (1/CU),
// XCD swizzle. ALL of K (64KB) and V (64KB) staged to LDS once in the
// prologue (128KB total) -> main loop has ZERO barriers and ZERO LDS writes.
// P stays in-register (cvt_pk_bf16 + permlane32/16 swaps). Softmax as exp2
// (Q pre-scaled by log2 e), no max subtraction (|S| bounded, fp32-safe).
// Waves start at staggered tiles to decorrelate pipe usage.

typedef __attribute__((ext_vector_type(4))) float f32x4;
typedef __attribute__((ext_vector_type(8))) short bf16x8;
typedef __attribute__((ext_vector_type(4))) unsigned u32x4;

#define KOFF 0         // 64 subtiles x 1KB, XOR-swizzled chunk layout
#define VOFF 65536     // 16 tiles x [32 d][64 j] bf16, XOR-swizzled rows

__device__ __forceinline__ unsigned cvtpk(float a, float b) {
    unsigned r;  // r.lo = bf16(a), r.hi = bf16(b), RNE
    asm("v_cvt_pk_bf16_f32 %0, %1, %2" : "=v"(r) : "v"(a), "v"(b));
    return r;
}
#define SWAP32(a, b) asm("v_permlane32_swap_b32 %0, %1" : "+v"(a), "+v"(b))
#define SWAP16(a, b) asm("v_permlane16_swap_b32 %0, %1" : "+v"(a), "+v"(b))

__device__ __forceinline__ float exp2fast(float x) {
#if __has_builtin(__builtin_amdgcn_exp2f)
    return __builtin_amdgcn_exp2f(x);
#else
    return exp2f(x);
#endif
}

__global__ __launch_bounds__(512, 2)
void attn_mse_kernel(const float* __restrict__ fs, const float* __restrict__ ft,
                     float* __restrict__ out)
{
    __shared__ __align__(16) unsigned char smem[131072];

    const int tid  = threadIdx.x;
    const int lane = tid & 63;
    const int w    = tid >> 6;     // wave 0..7
    const int g    = lane >> 4;    // 0..3
    const int c    = lane & 15;

    // XCD swizzle: 8 pairs x 4 q-blocks per XCD (bid%8) -> 2MB L2 set.
    const int bid  = blockIdx.x;
    const int pair = (bid & 7) * 8 + ((bid >> 3) & 7);
    const int q0   = (bid >> 6) * 256;

    const float* qb = fs + (size_t)pair * 32768;  // Q and V source
    const float* kb = ft + (size_t)pair * 32768;  // K source + loss target

    // Chunk-staging lane roles: word(dp,j) = p*64 + 16*(j>>2) + 4*((j&3)^p) + g
    // where dp = 4p+g (d-pair). Read side: fragment = 16B at (lane^g)*16.
    const int p_ = c >> 2, jq = c & 3;
    const int dp = 4 * p_ + g;
    const int w0 = p_ * 64 + 16 * jq + 4 * (0 ^ p_) + g;
    const int w1 = p_ * 64 + 16 * jq + 4 * (1 ^ p_) + g;
    const int w2 = p_ * 64 + 16 * jq + 4 * (2 ^ p_) + g;
    const int w3 = p_ * 64 + 16 * jq + 4 * (3 ^ p_) + g;

    // ---- stage Q (2 subtiles, pre-scaled by log2 e) into V region scratch
    {
        const float sc = 1.44269504f;
        #pragma unroll
        for (int st = 0; st < 2; ++st) {
            const float* r0 = qb + (size_t)(2 * dp) * 1024 + (q0 + w * 32 + st * 16) + 4 * jq;
            const float4 a = *(const float4*)(r0);
            const float4 b = *(const float4*)(r0 + 1024);
            unsigned* dst = (unsigned*)(smem + VOFF + w * 2048 + st * 1024);
            dst[w0] = cvtpk(a.x * sc, b.x * sc);
            dst[w1] = cvtpk(a.y * sc, b.y * sc);
            dst[w2] = cvtpk(a.z * sc, b.z * sc);
            dst[w3] = cvtpk(a.w * sc, b.w * sc);
        }
    }
    const bf16x8 qf0 = *(const bf16x8*)(smem + VOFF + w * 2048 + ((lane ^ g) << 4));
    const bf16x8 qf1 = *(const bf16x8*)(smem + VOFF + w * 2048 + 1024 + ((lane ^ g) << 4));
    __syncthreads();   // all Q reads done before V staging overwrites

    // ---- stage ALL K: wave w -> subtiles w*8..w*8+7 (j = w*128..+127)
    #pragma unroll
    for (int st = 0; st < 8; ++st) {
        const float* r0 = kb + (size_t)(2 * dp) * 1024 + (w * 128 + st * 16) + 4 * jq;
        const float4 a = *(const float4*)(r0);
        const float4 b = *(const float4*)(r0 + 1024);
        unsigned* dst = (unsigned*)(smem + KOFF + (w * 8 + st) * 1024);
        dst[w0] = cvtpk(a.x, b.x);
        dst[w1] = cvtpk(a.y, b.y);
        dst[w2] = cvtpk(a.z, b.z);
        dst[w3] = cvtpk(a.w, b.w);
    }
    // ---- stage ALL V: thread stages row d = w*4+g, j-quad 4c, all 16 tiles
    {
        const int dv = w * 4 + g;
        #pragma unroll
        for (int tt = 0; tt < 16; ++tt) {
            const float4 vv = *(const float4*)(qb + (size_t)dv * 1024 + tt * 64 + 4 * c);
            const unsigned lo = cvtpk(vv.x, vv.y), hi = cvtpk(vv.z, vv.w);
            *(unsigned long long*)(smem + VOFF + tt * 4096 + dv * 128 +
                                   ((8 * c) ^ ((dv & 7) << 4))) =
                (unsigned long long)lo | ((unsigned long long)hi << 32);
        }
    }
    __syncthreads();   // K/V fully resident; loop below is barrier-free

    f32x4 O[2][2];  // [i-subtile][d-half]
    #pragma unroll
    for (int a = 0; a < 2; ++a)
        #pragma unroll
        for (int b = 0; b < 2; ++b)
            O[a][b] = f32x4{0.f, 0.f, 0.f, 0.f};
    float l0 = 0.f, l1 = 0.f;  // softmax denom partials (q-row i = c)

    for (int t = 0; t < 16; ++t) {
        const int tabs = (t + 2 * w) & 15;   // staggered start per wave
        const unsigned char* bK = smem + KOFF + tabs * 4096;
        const unsigned char* bV = smem + VOFF + tabs * 4096;

        bf16x8 kf[4], vb[2][2];
        #pragma unroll
        for (int Mt = 0; Mt < 4; ++Mt)
            kf[Mt] = *(const bf16x8*)(bK + Mt * 1024 + ((lane ^ g) << 4));
        #pragma unroll
        for (int ks = 0; ks < 2; ++ks)
            #pragma unroll
            for (int df = 0; df < 2; ++df)
                vb[ks][df] = *(const bf16x8*)(bV + (c + 16 * df) * 128 +
                               (((unsigned)(ks * 64 + g * 16)) ^ ((c & 7) << 4)));

        // ST = K * Q^T : lane holds j = 16Mt + 4g + r, i = c (per subtile)
        f32x4 S[4][2];
        __builtin_amdgcn_s_setprio(1);
        #pragma unroll
        for (int Mt = 0; Mt < 4; ++Mt) {
            const f32x4 z = {0.f, 0.f, 0.f, 0.f};
            S[Mt][0] = __builtin_amdgcn_mfma_f32_16x16x32_bf16(kf[Mt], qf0, z, 0, 0, 0);
            S[Mt][1] = __builtin_amdgcn_mfma_f32_16x16x32_bf16(kf[Mt], qf1, z, 0, 0, 0);
        }
        __builtin_amdgcn_s_setprio(0);

        // P = exp2(S') = exp(sim); no max subtraction (fp32-safe)
        float ps0 = 0.f, ps1 = 0.f;
        #pragma unroll
        for (int Mt = 0; Mt < 4; ++Mt)
            #pragma unroll
            for (int r = 0; r < 4; ++r) {
                const float pv0 = exp2fast(S[Mt][0][r]);
                const float pv1 = exp2fast(S[Mt][1][r]);
                S[Mt][0][r] = pv0; ps0 += pv0;
                S[Mt][1][r] = pv1; ps1 += pv1;
            }
        l0 += ps0; l1 += ps1;

        // P fragments in-register: cvt_pk pairs + permlane 32/16 swaps.
        // After swaps, lane (g,c) element e holds P[i=c][j = 32ks + 8g + e].
        #pragma unroll
        for (int is = 0; is < 2; ++is) {
            #pragma unroll
            for (int ks = 0; ks < 2; ++ks) {
                unsigned u0 = cvtpk(S[2 * ks][is][0],     S[2 * ks][is][1]);
                unsigned u1 = cvtpk(S[2 * ks][is][2],     S[2 * ks][is][3]);
                unsigned u2 = cvtpk(S[2 * ks + 1][is][0], S[2 * ks + 1][is][1]);
                unsigned u3 = cvtpk(S[2 * ks + 1][is][2], S[2 * ks + 1][is][3]);
                SWAP32(u0, u2); SWAP32(u1, u3);
                SWAP16(u0, u2); SWAP16(u1, u3);
                const u32x4 pw = {u0, u1, u2, u3};
                const bf16x8 pa = __builtin_bit_cast(bf16x8, pw);
                __builtin_amdgcn_s_setprio(1);
                O[is][0] = __builtin_amdgcn_mfma_f32_16x16x32_bf16(pa, vb[ks][0], O[is][0], 0, 0, 0);
                O[is][1] = __builtin_amdgcn_mfma_f32_16x16x32_bf16(pa, vb[ks][1], O[is][1], 0, 0, 0);
                __builtin_amdgcn_s_setprio(0);
            }
        }
    }

    // ---- softmax denominators (reduce over g groups; lane gets row c's sum)
    l0 += __shfl_xor(l0, 16); l0 += __shfl_xor(l0, 32);
    l1 += __shfl_xor(l1, 16); l1 += __shfl_xor(l1, 32);
    const float li0 = 1.0f / l0;
    const float li1 = 1.0f / l1;

    // ---- loss: lane holds O rows i = 4g+r, cols d = c / c+16
    float acc = 0.f;
    const int n0 = q0 + w * 32;
    #pragma unroll
    for (int is = 0; is < 2; ++is) {
        const float liv = is ? li1 : li0;
        #pragma unroll
        for (int r = 0; r < 4; ++r) {
            const float lr = __shfl(liv, g * 4 + r);  // denom of local row 4g+r
            const int n = n0 + is * 16 + g * 4 + r;
            #pragma unroll
            for (int Nd = 0; Nd < 2; ++Nd) {
                const int d = Nd * 16 + c;
                const float oo = O[is][Nd][r] * lr;
                const float tv = kb[(size_t)d * 1024 + n];
                const float e = oo - tv;
                acc += e * e;
            }
        }
    }
    #pragma unroll
    for (int off = 1; off < 64; off <<= 1) acc += __shfl_xor(acc, off);
    __syncthreads();   // done reading K region; reuse for reduction scratch
    float* lred = (float*)(smem);
    if (lane == 0) lred[w] = acc;
    __syncthreads();
    if (tid == 0) {
        float s = 0.f;
        #pragma unroll
        for (int i = 0; i < 8; ++i) s += lred[i];
        atomicAdd(out, s * (1.0f / 2097152.0f));
    }
}

extern "C" void kernel_launch(void* const* d_in, const int* in_sizes, int n_in,
                              void* d_out, int out_size, void* d_ws, size_t ws_size,
                              hipStream_t stream) {
    const float* fs = (const float*)d_in[0];
    const float* ft = (const float*)d_in[1];
    float* out = (float*)d_out;
    hipMemsetAsync(out, 0, sizeof(float), stream);
    attn_mse_kernel<<<dim3(256), dim3(512), 0, stream>>>(fs, ft, out);
}